// Round 12
// baseline (233.736 us; speedup 1.0000x reference)
//
#include <hip/hip_runtime.h>
#include <math.h>

#define NN 4096
#define DD 512
#define NC 10
#define NG 2

#define BM 128
#define BN 64
#define BK 32
#define NT (DD / BK)     // 16 K-steps
#define NTILES 4160      // 1056 TT + 1056 SS + 2048 TS (= 8 * 520)

typedef __bf16 bf16x8 __attribute__((ext_vector_type(8)));
typedef __bf16 bf16x4 __attribute__((ext_vector_type(4)));
typedef float f32x4 __attribute__((ext_vector_type(4)));

__device__ __forceinline__ void load_lds16(const __bf16* g, __bf16* l) {
    __builtin_amdgcn_global_load_lds((const __attribute__((address_space(1))) void*)g,
                                     (__attribute__((address_space(3))) void*)l, 16, 0, 0);
}

__device__ __forceinline__ float agent_ld(const float* p) {
    return __hip_atomic_load(p, __ATOMIC_RELAXED, __HIP_MEMORY_SCOPE_AGENT);
}

// ---------------------------------------------------------------------------
// Kernel 1: fused fp32->bf16 convert + per-row squared norms (fp32 exact)
// + zeroing of the accumulator region. (unchanged)
// ---------------------------------------------------------------------------
__global__ void k_prep(const float* __restrict__ ft, const float* __restrict__ fs,
                       __bf16* __restrict__ at, __bf16* __restrict__ as_,
                       float* __restrict__ nt, float* __restrict__ ns,
                       float* __restrict__ zero_base) {
    if (blockIdx.x < 69) {
        int idx = blockIdx.x * 256 + threadIdx.x;
        if (idx < 17412) zero_base[idx] = 0.0f;
    }
    int wid  = threadIdx.x >> 6;
    int lane = threadIdx.x & 63;
    int r = blockIdx.x * 4 + wid;
    const float* src; __bf16* bdst; float* ndst; int row;
    if (r < NN) { src = ft; bdst = at;  ndst = nt; row = r; }
    else        { src = fs; bdst = as_; ndst = ns; row = r - NN; }
    const float4* p = (const float4*)(src + (size_t)row * DD);
    float s = 0.0f;
#pragma unroll
    for (int c = 0; c < 2; ++c) {
        float4 v = p[lane + 64 * c];
        s += v.x * v.x + v.y * v.y + v.z * v.z + v.w * v.w;
        bf16x4 b;
        b[0] = (__bf16)v.x; b[1] = (__bf16)v.y; b[2] = (__bf16)v.z; b[3] = (__bf16)v.w;
        *(bf16x4*)(bdst + (size_t)row * DD + (lane + 64 * c) * 4) = b;
    }
#pragma unroll
    for (int o = 32; o; o >>= 1) s += __shfl_xor(s, o);
    if (lane == 0) ndst[row] = s;
}

// ---------------------------------------------------------------------------
// Kernel 2: column sums + (last block) closed-form sigma -> invscale.
// (unchanged)
// ---------------------------------------------------------------------------
__global__ void k_colsums(const float* __restrict__ ft, const float* __restrict__ fs,
                          float* __restrict__ sumT, float* __restrict__ sumS,
                          const float* __restrict__ nt, const float* __restrict__ ns,
                          float* __restrict__ invscale, unsigned int* __restrict__ cnt) {
    int b = blockIdx.x;
    int mat = b & 1;
    int chunk = b >> 1;
    const float* src = mat ? fs : ft;
    float* dst = mat ? sumS : sumT;
    int r0 = chunk * 32;
    int c0 = threadIdx.x, c1 = threadIdx.x + 256;
    float a0 = 0.0f, a1 = 0.0f;
    for (int r = r0; r < r0 + 32; ++r) {
        a0 += src[(size_t)r * DD + c0];
        a1 += src[(size_t)r * DD + c1];
    }
    atomicAdd(&dst[c0], a0);
    atomicAdd(&dst[c1], a1);

    __shared__ int amLast;
    __threadfence();
    __syncthreads();
    if (threadIdx.x == 0) amLast = (atomicAdd(cnt, 1u) == 255u) ? 1 : 0;
    __syncthreads();
    if (!amLast) return;
    __threadfence();

    __shared__ float red[8];
    int tid = threadIdx.x;
    float s = 0.0f;
    for (int i = tid; i < NN; i += 256) s += nt[i] + ns[i];
    float d = 0.0f;
    for (int i = tid; i < DD; i += 256) d += agent_ld(&sumT[i]) * agent_ld(&sumS[i]);
#pragma unroll
    for (int o = 32; o; o >>= 1) { s += __shfl_xor(s, o); d += __shfl_xor(d, o); }
    int wid = tid >> 6, lane = tid & 63;
    if (lane == 0) { red[wid] = s; red[wid + 4] = d; }
    __syncthreads();
    if (tid == 0) {
        float S  = red[0] + red[1] + red[2] + red[3];
        float Dt = red[4] + red[5] + red[6] + red[7];
        float sigma = S / (float)NN - 2.0f * Dt / ((float)NN * (float)NN);
        invscale[0] = 1.0f / (2.0f * sigma);
    }
}

// ---------------------------------------------------------------------------
// Kernel 3: all three Grams. SMALL-WAVE config for register-bound occupancy:
// 128x64 tile, 4 waves (2Mx2N), wave tile 64x32 -> acc[4][2] (32 AGPR vs 64),
// ~90 regs/wave -> 5 waves/SIMD (20 waves/CU) vs r8's 4 (17).
// K-loop/staging structure identical to r8: BK=32, double-buffered
// stage-ahead, 3 global_load_lds/thread/step, conflict-free [kq][row][8] LDS
// (24 KB total). Tiles: [0,1056) TT triangle (bj>=2bi over 32x64 grid),
// [1056,2112) SS triangle, [2112,4160) TS full 32x64.
// XCD swizzle: swz = (bid&7)*520 + bid>>3 (4160 = 8*520, bijective).
// Sym element rule: c>r -> row+col add; c==r -> row only; c<r -> skip.
// ---------------------------------------------------------------------------
__global__ __launch_bounds__(256, 4) void k_gram_all(
    const __bf16* __restrict__ T, const __bf16* __restrict__ S,
    const float* __restrict__ nt, const float* __restrict__ ns,
    const int* __restrict__ labels, const int* __restrict__ groups,
    const float* __restrict__ invscale_p,
    float* __restrict__ zTT, float* __restrict__ zSS, float* __restrict__ zTS) {

    __shared__ __bf16 As[2][4 * 128 * 8];   // 8 KB per buffer
    __shared__ __bf16 Bs[2][4 * 64 * 8];    // 4 KB per buffer

    int swz = ((int)blockIdx.x & 7) * 520 + ((int)blockIdx.x >> 3);
    int mode, bi, bj;
    if (swz < 2112) {
        mode = (swz < 1056) ? 0 : 1;
        int k = (swz < 1056) ? swz : swz - 1056;
        int t = 0;
        while (k >= 64 - 2 * t) { k -= 64 - 2 * t; ++t; }   // uniform, <=32 iters
        bi = t; bj = 2 * t + k;
    } else {
        mode = 2;
        int k = swz - 2112;
        bi = k >> 6; bj = k & 63;
    }

    const __bf16* A = (mode == 1) ? S : T;
    const __bf16* B = (mode == 0) ? T : S;
    const float* nA = (mode == 1) ? ns : nt;
    const float* nB = (mode == 0) ? nt : ns;
    float* z0 = (mode == 0) ? zTT : ((mode == 1) ? zSS : zTS);
    float* z1 = zTS + NN;

    int tid = threadIdx.x;
    int i0 = bi * BM;
    int j0 = bj * BN;

    int lane = tid & 63, wid = tid >> 6;
    int wr = wid >> 1, wc = wid & 1;          // 2 x 2 wave grid
    int l15 = lane & 15, l4 = lane >> 4;

    // staging: A slots tid, tid+256 (row = tid&127, kq = tid>>7 and +2);
    //          B slot tid (row = tid&63, kq = tid>>6).
    int ra = tid & 127;
    int qa = tid >> 7;                        // 0..1
    int rb = tid & 63;
    int qb = tid >> 6;                        // 0..3
    const __bf16* gA = A + (size_t)(i0 + ra) * DD + qa * 8;   // +16 = chunk qa+2
    const __bf16* gB = B + (size_t)(j0 + rb) * DD + qb * 8;

    f32x4 acc[4][2] = {};

    load_lds16(gA,      &As[0][(size_t)tid * 8]);
    load_lds16(gA + 16, &As[0][(size_t)(tid + 256) * 8]);
    load_lds16(gB,      &Bs[0][(size_t)tid * 8]);
    __syncthreads();

#pragma unroll 2
    for (int t = 0; t < NT; ++t) {
        int b = t & 1;
        if (t < NT - 1) {
            int k0 = (t + 1) * BK;
            load_lds16(gA + k0,      &As[b ^ 1][(size_t)tid * 8]);
            load_lds16(gA + k0 + 16, &As[b ^ 1][(size_t)(tid + 256) * 8]);
            load_lds16(gB + k0,      &Bs[b ^ 1][(size_t)tid * 8]);
        }
        bf16x8 af[4], bfr[2];
#pragma unroll
        for (int im = 0; im < 4; ++im)
            af[im] = *(const bf16x8*)&As[b][((size_t)l4 * 128 + wr * 64 + im * 16 + l15) * 8];
#pragma unroll
        for (int in = 0; in < 2; ++in)
            bfr[in] = *(const bf16x8*)&Bs[b][((size_t)l4 * 64 + wc * 32 + in * 16 + l15) * 8];
#pragma unroll
        for (int im = 0; im < 4; ++im)
#pragma unroll
            for (int in = 0; in < 2; ++in)
                acc[im][in] = __builtin_amdgcn_mfma_f32_16x16x32_bf16(af[im], bfr[in], acc[im][in], 0, 0, 0);
        __syncthreads();
    }

    // epilogue: D = nA + nB - 2*dot -> exp -> predicate -> row/col sums
    float inv_scale = invscale_p[0];
    int ibase = i0 + wr * 64;
    int jbase = j0 + wc * 32;
    float nBv[2];
    int labBv[2], grpBv[2];
#pragma unroll
    for (int in = 0; in < 2; ++in) {
        int j = jbase + in * 16 + l15;
        nBv[in] = nB[j];
        labBv[in] = labels[j];
        grpBv[in] = groups[j];
    }
    float cs[2] = {0.0f, 0.0f};               // sym col sums (c > r)
#pragma unroll
    for (int im = 0; im < 4; ++im) {
#pragma unroll
        for (int j = 0; j < 4; ++j) {
            int row = ibase + im * 16 + l4 * 4 + j;
            float ni = nA[row];
            int li = labels[row];
            int gi = groups[row];
            float s0 = 0.0f, s1 = 0.0f;
#pragma unroll
            for (int in = 0; in < 2; ++in) {
                float d = ni + nBv[in] - 2.0f * acc[im][in][j];
                d = fmaxf(d, 1e-12f);
                float kv = __expf(-d * inv_scale);
                bool ok = (li == labBv[in]);
                if (mode == 1) ok = ok && (gi == grpBv[in]);
                if (mode == 2) {
                    s0 += (ok && grpBv[in] == 0) ? kv : 0.0f;
                    s1 += (ok && grpBv[in] == 1) ? kv : 0.0f;
                } else {
                    int c = jbase + in * 16 + l15;
                    s0     += (ok && c >= row) ? kv : 0.0f;
                    cs[in] += (ok && c >  row) ? kv : 0.0f;
                }
            }
#pragma unroll
            for (int o = 1; o < 16; o <<= 1) {
                s0 += __shfl_xor(s0, o);
                if (mode == 2) s1 += __shfl_xor(s1, o);
            }
            if (l15 == 0) {
                atomicAdd(&z0[row], s0);
                if (mode == 2) atomicAdd(&z1[row], s1);
            }
        }
    }
    if (mode != 2) {
#pragma unroll
        for (int in = 0; in < 2; ++in) {
            cs[in] += __shfl_xor(cs[in], 16);
            cs[in] += __shfl_xor(cs[in], 32);
        }
        if (l4 == 0) {
#pragma unroll
            for (int in = 0; in < 2; ++in)
                atomicAdd(&z0[jbase + in * 16 + l15], cs[in]);
        }
    }
}

// ---------------------------------------------------------------------------
// Kernel 4: bucket per-row sums, final scalar. (unchanged)
// ---------------------------------------------------------------------------
__global__ void k_final(const int* __restrict__ labels, const int* __restrict__ groups,
                        const float* __restrict__ zTT, const float* __restrict__ zSS,
                        const float* __restrict__ zTS, float* __restrict__ out) {
    __shared__ float cnt_t[NC], cnt_s[NC * NG];
    __shared__ float nTT[NC], nSS[NC * NG], nTS[NC * NG];
    int tid = threadIdx.x;
    if (tid < NC) { cnt_t[tid] = 0.0f; nTT[tid] = 0.0f; }
    if (tid < NC * NG) { cnt_s[tid] = 0.0f; nSS[tid] = 0.0f; nTS[tid] = 0.0f; }
    __syncthreads();
    for (int i = tid; i < NN; i += 256) {
        int l = labels[i], g = groups[i];
        atomicAdd(&cnt_t[l], 1.0f);
        atomicAdd(&cnt_s[l * NG + g], 1.0f);
        atomicAdd(&nTT[l], zTT[i]);
        atomicAdd(&nSS[l * NG + g], zSS[i]);
        atomicAdd(&nTS[l * NG + 0], zTS[i]);
        atomicAdd(&nTS[l * NG + 1], zTS[NN + i]);
    }
    __syncthreads();
    if (tid == 0) {
        float total = 0.0f;
        for (int c = 0; c < NC; ++c) {
            float ntc = cnt_t[c];
            float sn = fmaxf(ntc, 1.0f);
            float meanTT = nTT[c] / (sn * sn);
            for (int g = 0; g < NG; ++g) {
                float nsg = cnt_s[c * NG + g];
                float ss = fmaxf(nsg, 1.0f);
                float meanSS = nSS[c * NG + g] / (ss * ss);
                float meanTS = nTS[c * NG + g] / (sn * ss);
                if (ntc > 0.0f && nsg > 0.0f)
                    total += meanTT + meanSS - 2.0f * meanTS;
            }
        }
        out[0] = 0.5f * total;
    }
}

// ---------------------------------------------------------------------------
// workspace layout:
// bytes [0, 4MB)      : teacher bf16 [4096][512]
// bytes [4MB, 8MB)    : student bf16 [4096][512]
// floats from 8MB (wsf):
//   +0      nt[4096]
//   +4096   ns[4096]
//   +8192   sumT[512]      <- zero region start (17412 floats)
//   +8704   sumS[512]
//   +9216   zTT[4096]
//   +13312  zSS[4096]
//   +17408  zTS[2*4096]
//   +25600  invscale[1]
//   +25601  counter_colsums (uint)
//   +25602  (spare, zeroed)
// ---------------------------------------------------------------------------
extern "C" void kernel_launch(void* const* d_in, const int* in_sizes, int n_in,
                              void* d_out, int out_size, void* d_ws, size_t ws_size,
                              hipStream_t stream) {
    const float* fs     = (const float*)d_in[0];
    const float* ft     = (const float*)d_in[1];
    const int*   groups = (const int*)d_in[2];
    const int*   labels = (const int*)d_in[3];

    __bf16* Abf = (__bf16*)d_ws;                       // teacher
    __bf16* Bbf = (__bf16*)d_ws + (size_t)NN * DD;     // student
    float* wsf  = (float*)((char*)d_ws + (size_t)2 * NN * DD * sizeof(__bf16));
    float* nt   = wsf;
    float* ns   = wsf + 4096;
    float* sumT = wsf + 8192;
    float* sumS = wsf + 8704;
    float* zTT  = wsf + 9216;
    float* zSS  = wsf + 13312;
    float* zTS  = wsf + 17408;
    float* invs = wsf + 25600;
    unsigned int* cntC = (unsigned int*)(wsf + 25601);

    k_prep<<<2048, 256, 0, stream>>>(ft, fs, Abf, Bbf, nt, ns, wsf + 8192);
    k_colsums<<<256, 256, 0, stream>>>(ft, fs, sumT, sumS, nt, ns, invs, cntC);
    k_gram_all<<<NTILES, 256, 0, stream>>>(Abf, Bbf, nt, ns, labels, groups,
                                           invs, zTT, zSS, zTS);
    k_final<<<1, 256, 0, stream>>>(labels, groups, zTT, zSS, zTS, (float*)d_out);
}

// Round 13
// 169.316 us; speedup vs baseline: 1.3805x; 1.3805x over previous
//
#include <hip/hip_runtime.h>
#include <math.h>

#define NN 4096
#define DD 512
#define NC 10
#define NG 2

#define BM 128
#define BN 128
#define BK 32
#define NT (DD / BK)     // 16 K-steps
#define NTILES 2080      // 528 TT + 528 SS + 1024 TS (= 8 * 260)

typedef __bf16 bf16x8 __attribute__((ext_vector_type(8)));
typedef __bf16 bf16x4 __attribute__((ext_vector_type(4)));
typedef float f32x4 __attribute__((ext_vector_type(4)));

__device__ __forceinline__ void load_lds16(const __bf16* g, __bf16* l) {
    __builtin_amdgcn_global_load_lds((const __attribute__((address_space(1))) void*)g,
                                     (__attribute__((address_space(3))) void*)l, 16, 0, 0);
}

// ---------------------------------------------------------------------------
// Kernel 1: fused fp32->bf16 convert + per-row squared norms (fp32 exact)
// + zeroing of zTT/zSS/zTS/invscale (16385 floats from wsf+9216).
// ---------------------------------------------------------------------------
__global__ void k_prep(const float* __restrict__ ft, const float* __restrict__ fs,
                       __bf16* __restrict__ at, __bf16* __restrict__ as_,
                       float* __restrict__ nt, float* __restrict__ ns,
                       float* __restrict__ zero_base) {
    if (blockIdx.x < 65) {
        int idx = blockIdx.x * 256 + threadIdx.x;
        if (idx < 16385) zero_base[idx] = 0.0f;
    }
    int wid  = threadIdx.x >> 6;
    int lane = threadIdx.x & 63;
    int r = blockIdx.x * 4 + wid;
    const float* src; __bf16* bdst; float* ndst; int row;
    if (r < NN) { src = ft; bdst = at;  ndst = nt; row = r; }
    else        { src = fs; bdst = as_; ndst = ns; row = r - NN; }
    const float4* p = (const float4*)(src + (size_t)row * DD);
    float s = 0.0f;
#pragma unroll
    for (int c = 0; c < 2; ++c) {
        float4 v = p[lane + 64 * c];
        s += v.x * v.x + v.y * v.y + v.z * v.z + v.w * v.w;
        bf16x4 b;
        b[0] = (__bf16)v.x; b[1] = (__bf16)v.y; b[2] = (__bf16)v.z; b[3] = (__bf16)v.w;
        *(bf16x4*)(bdst + (size_t)row * DD + (lane + 64 * c) * 4) = b;
    }
#pragma unroll
    for (int o = 32; o; o >>= 1) s += __shfl_xor(s, o);
    if (lane == 0) ndst[row] = s;
}

// ---------------------------------------------------------------------------
// Kernel 2: column partial sums, NO atomics. 32 blocks x 256 thr:
// block b: matrix = b>>4, row chunk = (b&15)*256 .. +256. Each thread sums
// cols tid and tid+256 over the chunk -> psum[b*512 + col].
// ---------------------------------------------------------------------------
__global__ void k_colsums(const float* __restrict__ ft, const float* __restrict__ fs,
                          float* __restrict__ psum) {
    int b = blockIdx.x;
    const float* src = (b < 16) ? ft : fs;
    int r0 = (b & 15) * 256;
    int c0 = threadIdx.x, c1 = threadIdx.x + 256;
    float a0 = 0.0f, a1 = 0.0f;
    for (int r = r0; r < r0 + 256; ++r) {
        a0 += src[(size_t)r * DD + c0];
        a1 += src[(size_t)r * DD + c1];
    }
    psum[(size_t)b * 512 + c0] = a0;
    psum[(size_t)b * 512 + c1] = a1;
}

// ---------------------------------------------------------------------------
// Kernel 3: inv_scale = 1/(2*sigma_avg), sigma closed form:
// sigma = (sum nt + sum ns)/N - 2*(sumT . sumS)/N^2, sums from psum partials.
// ---------------------------------------------------------------------------
__global__ void k_scale(const float* __restrict__ nt, const float* __restrict__ ns,
                        const float* __restrict__ psum, float* __restrict__ invscale) {
    __shared__ float red[8];
    int tid = threadIdx.x;
    float s = 0.0f;
    for (int i = tid; i < NN; i += 256) s += nt[i] + ns[i];
    float d = 0.0f;
    for (int col = tid; col < DD; col += 256) {
        float st = 0.0f, ss = 0.0f;
#pragma unroll
        for (int b = 0; b < 16; ++b) {
            st += psum[(size_t)b * 512 + col];
            ss += psum[(size_t)(b + 16) * 512 + col];
        }
        d += st * ss;
    }
#pragma unroll
    for (int o = 32; o; o >>= 1) { s += __shfl_xor(s, o); d += __shfl_xor(d, o); }
    int wid = tid >> 6, lane = tid & 63;
    if (lane == 0) { red[wid] = s; red[wid + 4] = d; }
    __syncthreads();
    if (tid == 0) {
        float S  = red[0] + red[1] + red[2] + red[3];
        float Dt = red[4] + red[5] + red[6] + red[7];
        float sigma = S / (float)NN - 2.0f * Dt / ((float)NN * (float)NN);
        invscale[0] = 1.0f / (2.0f * sigma);
    }
}

// ---------------------------------------------------------------------------
// Kernel 4: all three Grams. 128x128 tile, 4 waves (2x2), wave tile 64x64
// (acc[4][4] -> r8's per-wave rate: 16 MFMA / 8 ds_read per step), BK=32,
// 32 KB LDS dbuf -> 4 blocks/CU (1024 concurrent) -> round quantum HALVED
// vs r8 (makespan ~3 x 20 us instead of 3 x 40.5).
// Tiles: [0,528) TT triangle (bj>=bi over 32x32), [528,1056) SS triangle,
// [1056,2080) TS full 32x32. Swizzle: swz=(bid&7)*260+bid>>3 (bijective).
// Sym element rule: c>r -> row+col add; c==r -> row only; c<r -> skip.
// ---------------------------------------------------------------------------
__global__ __launch_bounds__(256, 4) void k_gram_all(
    const __bf16* __restrict__ T, const __bf16* __restrict__ S,
    const float* __restrict__ nt, const float* __restrict__ ns,
    const int* __restrict__ labels, const int* __restrict__ groups,
    const float* __restrict__ invscale_p,
    float* __restrict__ zTT, float* __restrict__ zSS, float* __restrict__ zTS) {

    __shared__ __bf16 As[2][4 * 128 * 8];   // 8 KB per buffer
    __shared__ __bf16 Bs[2][4 * 128 * 8];   // 8 KB per buffer

    int swz = ((int)blockIdx.x & 7) * 260 + ((int)blockIdx.x >> 3);
    int mode, bi, bj;
    if (swz < 1056) {
        mode = (swz < 528) ? 0 : 1;
        int k = (swz < 528) ? swz : swz - 528;
        int t = 0;
        while (k >= 32 - t) { k -= 32 - t; ++t; }   // uniform, <=32 iters
        bi = t; bj = t + k;
    } else {
        mode = 2;
        int k = swz - 1056;
        bi = k >> 5; bj = k & 31;
    }

    const __bf16* A = (mode == 1) ? S : T;
    const __bf16* B = (mode == 0) ? T : S;
    const float* nA = (mode == 1) ? ns : nt;
    const float* nB = (mode == 0) ? nt : ns;
    float* z0 = (mode == 0) ? zTT : ((mode == 1) ? zSS : zTS);
    float* z1 = zTS + NN;

    int tid = threadIdx.x;
    int i0 = bi * BM;
    int j0 = bj * BN;

    int lane = tid & 63, wid = tid >> 6;
    int wr = wid >> 1, wc = wid & 1;          // 2 x 2 wave grid
    int l15 = lane & 15, l4 = lane >> 4;

    // staging: slots s and s+256 per matrix; slot s: row = s&127, kq = s>>7
    int ra = tid & 127;
    int qa = tid >> 7;                        // 0..1
    const __bf16* gA = A + (size_t)(i0 + ra) * DD + qa * 8;   // +16 = chunk qa+2
    const __bf16* gB = B + (size_t)(j0 + ra) * DD + qa * 8;

    f32x4 acc[4][4] = {};

    load_lds16(gA,      &As[0][(size_t)tid * 8]);
    load_lds16(gA + 16, &As[0][(size_t)(tid + 256) * 8]);
    load_lds16(gB,      &Bs[0][(size_t)tid * 8]);
    load_lds16(gB + 16, &Bs[0][(size_t)(tid + 256) * 8]);
    __syncthreads();

#pragma unroll 2
    for (int t = 0; t < NT; ++t) {
        int b = t & 1;
        if (t < NT - 1) {
            int k0 = (t + 1) * BK;
            load_lds16(gA + k0,      &As[b ^ 1][(size_t)tid * 8]);
            load_lds16(gA + k0 + 16, &As[b ^ 1][(size_t)(tid + 256) * 8]);
            load_lds16(gB + k0,      &Bs[b ^ 1][(size_t)tid * 8]);
            load_lds16(gB + k0 + 16, &Bs[b ^ 1][(size_t)(tid + 256) * 8]);
        }
        bf16x8 af[4], bfr[4];
#pragma unroll
        for (int im = 0; im < 4; ++im)
            af[im] = *(const bf16x8*)&As[b][((size_t)l4 * 128 + wr * 64 + im * 16 + l15) * 8];
#pragma unroll
        for (int in = 0; in < 4; ++in)
            bfr[in] = *(const bf16x8*)&Bs[b][((size_t)l4 * 128 + wc * 64 + in * 16 + l15) * 8];
#pragma unroll
        for (int im = 0; im < 4; ++im)
#pragma unroll
            for (int in = 0; in < 4; ++in)
                acc[im][in] = __builtin_amdgcn_mfma_f32_16x16x32_bf16(af[im], bfr[in], acc[im][in], 0, 0, 0);
        __syncthreads();
    }

    // epilogue: D = nA + nB - 2*dot -> exp -> predicate -> row/col sums
    float inv_scale = invscale_p[0];
    int ibase = i0 + wr * 64;
    int jbase = j0 + wc * 64;
    float nBv[4];
    int labBv[4], grpBv[4];
#pragma unroll
    for (int in = 0; in < 4; ++in) {
        int j = jbase + in * 16 + l15;
        nBv[in] = nB[j];
        labBv[in] = labels[j];
        grpBv[in] = groups[j];
    }
    float cs[4] = {0.0f, 0.0f, 0.0f, 0.0f};   // sym col sums (c > r)
#pragma unroll
    for (int im = 0; im < 4; ++im) {
#pragma unroll
        for (int j = 0; j < 4; ++j) {
            int row = ibase + im * 16 + l4 * 4 + j;
            float ni = nA[row];
            int li = labels[row];
            int gi = groups[row];
            float s0 = 0.0f, s1 = 0.0f;
#pragma unroll
            for (int in = 0; in < 4; ++in) {
                float d = ni + nBv[in] - 2.0f * acc[im][in][j];
                d = fmaxf(d, 1e-12f);
                float kv = __expf(-d * inv_scale);
                bool ok = (li == labBv[in]);
                if (mode == 1) ok = ok && (gi == grpBv[in]);
                if (mode == 2) {
                    s0 += (ok && grpBv[in] == 0) ? kv : 0.0f;
                    s1 += (ok && grpBv[in] == 1) ? kv : 0.0f;
                } else {
                    int c = jbase + in * 16 + l15;
                    s0     += (ok && c >= row) ? kv : 0.0f;
                    cs[in] += (ok && c >  row) ? kv : 0.0f;
                }
            }
#pragma unroll
            for (int o = 1; o < 16; o <<= 1) {
                s0 += __shfl_xor(s0, o);
                if (mode == 2) s1 += __shfl_xor(s1, o);
            }
            if (l15 == 0) {
                atomicAdd(&z0[row], s0);
                if (mode == 2) atomicAdd(&z1[row], s1);
            }
        }
    }
    if (mode != 2) {
#pragma unroll
        for (int in = 0; in < 4; ++in) {
            cs[in] += __shfl_xor(cs[in], 16);
            cs[in] += __shfl_xor(cs[in], 32);
        }
        if (l4 == 0) {
#pragma unroll
            for (int in = 0; in < 4; ++in)
                atomicAdd(&z0[jbase + in * 16 + l15], cs[in]);
        }
    }
}

// ---------------------------------------------------------------------------
// Kernel 5: final bucket reduction, register-bucketed (no data-dependent
// atomics in the hot loop; compile-time-indexed unrolled arrays per rule #20).
// red layout: [0..9] cntT, [10..29] cntS, [30..39] sTT, [40..59] sSS, [60..79] sTS
// ---------------------------------------------------------------------------
__global__ void k_final(const int* __restrict__ labels, const int* __restrict__ groups,
                        const float* __restrict__ zTT, const float* __restrict__ zSS,
                        const float* __restrict__ zTS, float* __restrict__ out) {
    __shared__ float red[80];
    int tid = threadIdx.x;
    float cT[NC] = {}, cS[NC * NG] = {};
    float sTT[NC] = {}, sSS[NC * NG] = {}, sTS[NC * NG] = {};
    for (int i = tid; i < NN; i += 256) {
        int l = labels[i], g = groups[i];
        float vTT = zTT[i], vSS = zSS[i];
        float vT0 = zTS[i], vT1 = zTS[NN + i];
#pragma unroll
        for (int c = 0; c < NC; ++c) {
            bool m  = (l == c);
            bool m0 = m && (g == 0);
            bool m1 = m && (g == 1);
            cT[c]          += m  ? 1.0f : 0.0f;
            sTT[c]         += m  ? vTT  : 0.0f;
            cS[2 * c]      += m0 ? 1.0f : 0.0f;
            cS[2 * c + 1]  += m1 ? 1.0f : 0.0f;
            sSS[2 * c]     += m0 ? vSS  : 0.0f;
            sSS[2 * c + 1] += m1 ? vSS  : 0.0f;
            sTS[2 * c]     += m  ? vT0  : 0.0f;
            sTS[2 * c + 1] += m  ? vT1  : 0.0f;
        }
    }
#pragma unroll
    for (int o = 32; o; o >>= 1) {
#pragma unroll
        for (int c = 0; c < NC; ++c) {
            cT[c]  += __shfl_xor(cT[c], o);
            sTT[c] += __shfl_xor(sTT[c], o);
        }
#pragma unroll
        for (int p = 0; p < NC * NG; ++p) {
            cS[p]  += __shfl_xor(cS[p], o);
            sSS[p] += __shfl_xor(sSS[p], o);
            sTS[p] += __shfl_xor(sTS[p], o);
        }
    }
    if (tid < 80) red[tid] = 0.0f;
    __syncthreads();
    if ((tid & 63) == 0) {
#pragma unroll
        for (int c = 0; c < NC; ++c) {
            atomicAdd(&red[c], cT[c]);
            atomicAdd(&red[30 + c], sTT[c]);
        }
#pragma unroll
        for (int p = 0; p < NC * NG; ++p) {
            atomicAdd(&red[10 + p], cS[p]);
            atomicAdd(&red[40 + p], sSS[p]);
            atomicAdd(&red[60 + p], sTS[p]);
        }
    }
    __syncthreads();
    if (tid == 0) {
        float total = 0.0f;
        for (int c = 0; c < NC; ++c) {
            float ntc = red[c];
            float sn = fmaxf(ntc, 1.0f);
            float meanTT = red[30 + c] / (sn * sn);
            for (int g = 0; g < NG; ++g) {
                float nsg = red[10 + 2 * c + g];
                float ss = fmaxf(nsg, 1.0f);
                float meanSS = red[40 + 2 * c + g] / (ss * ss);
                float meanTS = red[60 + 2 * c + g] / (sn * ss);
                if (ntc > 0.0f && nsg > 0.0f)
                    total += meanTT + meanSS - 2.0f * meanTS;
            }
        }
        out[0] = 0.5f * total;
    }
}

// ---------------------------------------------------------------------------
// workspace layout:
// bytes [0, 4MB)      : teacher bf16 [4096][512]
// bytes [4MB, 8MB)    : student bf16 [4096][512]
// floats from 8MB (wsf):
//   +0      nt[4096]
//   +4096   ns[4096]
//   +9216   zTT[4096]      <- zero region start (16385 floats)
//   +13312  zSS[4096]
//   +17408  zTS[2*4096]
//   +25600  invscale[1]    <- zero region end
//   +25604  psum[32*512]   (fully overwritten each call, no zeroing)
// ---------------------------------------------------------------------------
extern "C" void kernel_launch(void* const* d_in, const int* in_sizes, int n_in,
                              void* d_out, int out_size, void* d_ws, size_t ws_size,
                              hipStream_t stream) {
    const float* fs     = (const float*)d_in[0];
    const float* ft     = (const float*)d_in[1];
    const int*   groups = (const int*)d_in[2];
    const int*   labels = (const int*)d_in[3];

    __bf16* Abf = (__bf16*)d_ws;                       // teacher
    __bf16* Bbf = (__bf16*)d_ws + (size_t)NN * DD;     // student
    float* wsf  = (float*)((char*)d_ws + (size_t)2 * NN * DD * sizeof(__bf16));
    float* nt   = wsf;
    float* ns   = wsf + 4096;
    float* zTT  = wsf + 9216;
    float* zSS  = wsf + 13312;
    float* zTS  = wsf + 17408;
    float* invs = wsf + 25600;
    float* psum = wsf + 25604;

    k_prep<<<2048, 256, 0, stream>>>(ft, fs, Abf, Bbf, nt, ns, wsf + 9216);
    k_colsums<<<32, 256, 0, stream>>>(ft, fs, psum);
    k_scale<<<1, 256, 0, stream>>>(nt, ns, psum, invs);
    k_gram_all<<<NTILES, 256, 0, stream>>>(Abf, Bbf, nt, ns, labels, groups,
                                           invs, zTT, zSS, zTS);
    k_final<<<1, 256, 0, stream>>>(labels, groups, zTT, zSS, zTS, (float*)d_out);
}

// Round 14
// 151.462 us; speedup vs baseline: 1.5432x; 1.1179x over previous
//
#include <hip/hip_runtime.h>
#include <math.h>

#define NN 4096
#define DD 512
#define NC 10
#define NG 2

#define BM 128
#define BN 128
#define BK 32
#define NT (DD / BK)     // 16 K-steps
#define NTILES 2080      // 528 TT + 528 SS + 1024 TS (= 8 * 260)

typedef __bf16 bf16x8 __attribute__((ext_vector_type(8)));
typedef __bf16 bf16x4 __attribute__((ext_vector_type(4)));
typedef float f32x4 __attribute__((ext_vector_type(4)));

__device__ __forceinline__ void load_lds16(const __bf16* g, __bf16* l) {
    __builtin_amdgcn_global_load_lds((const __attribute__((address_space(1))) void*)g,
                                     (__attribute__((address_space(3))) void*)l, 16, 0, 0);
}

__device__ __forceinline__ float agent_ld(const float* p) {
    return __hip_atomic_load(p, __ATOMIC_RELAXED, __HIP_MEMORY_SCOPE_AGENT);
}

// ---------------------------------------------------------------------------
// Kernel 1: fused fp32->bf16 convert + per-row squared norms (fp32 exact).
// Block 0 zeroes the bucket/counter region (68 floats).
// ---------------------------------------------------------------------------
__global__ void k_prep(const float* __restrict__ ft, const float* __restrict__ fs,
                       __bf16* __restrict__ at, __bf16* __restrict__ as_,
                       float* __restrict__ nt, float* __restrict__ ns,
                       float* __restrict__ zero_base) {
    if (blockIdx.x == 0 && threadIdx.x < 68) zero_base[threadIdx.x] = 0.0f;
    int wid  = threadIdx.x >> 6;
    int lane = threadIdx.x & 63;
    int r = blockIdx.x * 4 + wid;
    const float* src; __bf16* bdst; float* ndst; int row;
    if (r < NN) { src = ft; bdst = at;  ndst = nt; row = r; }
    else        { src = fs; bdst = as_; ndst = ns; row = r - NN; }
    const float4* p = (const float4*)(src + (size_t)row * DD);
    float s = 0.0f;
#pragma unroll
    for (int c = 0; c < 2; ++c) {
        float4 v = p[lane + 64 * c];
        s += v.x * v.x + v.y * v.y + v.z * v.z + v.w * v.w;
        bf16x4 b;
        b[0] = (__bf16)v.x; b[1] = (__bf16)v.y; b[2] = (__bf16)v.z; b[3] = (__bf16)v.w;
        *(bf16x4*)(bdst + (size_t)row * DD + (lane + 64 * c) * 4) = b;
    }
#pragma unroll
    for (int o = 32; o; o >>= 1) s += __shfl_xor(s, o);
    if (lane == 0) ndst[row] = s;
}

// ---------------------------------------------------------------------------
// Kernel 2: column partial sums (64 blocks, no atomics) + last-finisher
// computes sigma (closed form) -> invscale. Fence protocol cheap at 64 blocks.
// ---------------------------------------------------------------------------
__global__ void k_colsums_scale(const float* __restrict__ ft, const float* __restrict__ fs,
                                float* __restrict__ psum,
                                const float* __restrict__ nt, const float* __restrict__ ns,
                                float* __restrict__ invscale, unsigned int* __restrict__ cnt) {
    int b = blockIdx.x;                     // 0..63
    const float* src = (b < 32) ? ft : fs;
    int r0 = (b & 31) * 128;
    int c0 = threadIdx.x, c1 = threadIdx.x + 256;
    float a0 = 0.0f, a1 = 0.0f;
    for (int r = r0; r < r0 + 128; ++r) {
        a0 += src[(size_t)r * DD + c0];
        a1 += src[(size_t)r * DD + c1];
    }
    psum[(size_t)b * 512 + c0] = a0;
    psum[(size_t)b * 512 + c1] = a1;

    __shared__ int amLast;
    __threadfence();
    __syncthreads();
    if (threadIdx.x == 0) amLast = (atomicAdd(cnt, 1u) == 63u) ? 1 : 0;
    __syncthreads();
    if (!amLast) return;
    __threadfence();

    __shared__ float red[8];
    int tid = threadIdx.x;
    float s = 0.0f;
    for (int i = tid; i < NN; i += 256) s += nt[i] + ns[i];
    float d = 0.0f;
    for (int col = tid; col < DD; col += 256) {
        float st = 0.0f, su = 0.0f;
#pragma unroll
        for (int p = 0; p < 32; ++p) {
            st += agent_ld(&psum[(size_t)p * 512 + col]);
            su += agent_ld(&psum[(size_t)(p + 32) * 512 + col]);
        }
        d += st * su;
    }
#pragma unroll
    for (int o = 32; o; o >>= 1) { s += __shfl_xor(s, o); d += __shfl_xor(d, o); }
    int wid = tid >> 6, lane = tid & 63;
    if (lane == 0) { red[wid] = s; red[wid + 4] = d; }
    __syncthreads();
    if (tid == 0) {
        float S  = red[0] + red[1] + red[2] + red[3];
        float Dt = red[4] + red[5] + red[6] + red[7];
        float sigma = S / (float)NN - 2.0f * Dt / ((float)NN * (float)NN);
        invscale[0] = 1.0f / (2.0f * sigma);
    }
}

// ---------------------------------------------------------------------------
// Kernel 3: all three Grams. K-loop byte-identical to round 13 (best:
// 128x128, 4 waves 2x2, wave tile 64x64, BK=32, dbuf stage-ahead, 32KB LDS,
// conflict-free [kq][row][8], swz=(bid&7)*260+bid>>3).
// NEW epilogue: per-block LDS bucket reduce (20 slots keyed by label/group;
// predicate guarantees row and col share a bucket) -> <=20 global atomics
// into gbkt[50] (0..9 TT, 10..29 SS, 30..49 TS). No z arrays, no k_final pass.
// ---------------------------------------------------------------------------
__global__ __launch_bounds__(256, 4) void k_gram_all(
    const __bf16* __restrict__ T, const __bf16* __restrict__ S,
    const float* __restrict__ nt, const float* __restrict__ ns,
    const int* __restrict__ labels, const int* __restrict__ groups,
    const float* __restrict__ invscale_p, float* __restrict__ gbkt) {

    __shared__ __bf16 As[2][4 * 128 * 8];   // 8 KB per buffer
    __shared__ __bf16 Bs[2][4 * 128 * 8];   // 8 KB per buffer
    __shared__ float lbkt[20];

    int swz = ((int)blockIdx.x & 7) * 260 + ((int)blockIdx.x >> 3);
    int mode, bi, bj;
    if (swz < 1056) {
        mode = (swz < 528) ? 0 : 1;
        int k = (swz < 528) ? swz : swz - 528;
        int t = 0;
        while (k >= 32 - t) { k -= 32 - t; ++t; }   // uniform, <=32 iters
        bi = t; bj = t + k;
    } else {
        mode = 2;
        int k = swz - 1056;
        bi = k >> 5; bj = k & 31;
    }

    const __bf16* A = (mode == 1) ? S : T;
    const __bf16* B = (mode == 0) ? T : S;
    const float* nA = (mode == 1) ? ns : nt;
    const float* nB = (mode == 0) ? nt : ns;

    int tid = threadIdx.x;
    if (tid < 20) lbkt[tid] = 0.0f;          // covered by prologue barrier
    int i0 = bi * BM;
    int j0 = bj * BN;

    int lane = tid & 63, wid = tid >> 6;
    int wr = wid >> 1, wc = wid & 1;          // 2 x 2 wave grid
    int l15 = lane & 15, l4 = lane >> 4;

    int ra = tid & 127;
    int qa = tid >> 7;                        // 0..1
    const __bf16* gA = A + (size_t)(i0 + ra) * DD + qa * 8;   // +16 = chunk qa+2
    const __bf16* gB = B + (size_t)(j0 + ra) * DD + qa * 8;

    f32x4 acc[4][4] = {};

    load_lds16(gA,      &As[0][(size_t)tid * 8]);
    load_lds16(gA + 16, &As[0][(size_t)(tid + 256) * 8]);
    load_lds16(gB,      &Bs[0][(size_t)tid * 8]);
    load_lds16(gB + 16, &Bs[0][(size_t)(tid + 256) * 8]);
    __syncthreads();

#pragma unroll 2
    for (int t = 0; t < NT; ++t) {
        int b = t & 1;
        if (t < NT - 1) {
            int k0 = (t + 1) * BK;
            load_lds16(gA + k0,      &As[b ^ 1][(size_t)tid * 8]);
            load_lds16(gA + k0 + 16, &As[b ^ 1][(size_t)(tid + 256) * 8]);
            load_lds16(gB + k0,      &Bs[b ^ 1][(size_t)tid * 8]);
            load_lds16(gB + k0 + 16, &Bs[b ^ 1][(size_t)(tid + 256) * 8]);
        }
        bf16x8 af[4], bfr[4];
#pragma unroll
        for (int im = 0; im < 4; ++im)
            af[im] = *(const bf16x8*)&As[b][((size_t)l4 * 128 + wr * 64 + im * 16 + l15) * 8];
#pragma unroll
        for (int in = 0; in < 4; ++in)
            bfr[in] = *(const bf16x8*)&Bs[b][((size_t)l4 * 128 + wc * 64 + in * 16 + l15) * 8];
#pragma unroll
        for (int im = 0; im < 4; ++im)
#pragma unroll
            for (int in = 0; in < 4; ++in)
                acc[im][in] = __builtin_amdgcn_mfma_f32_16x16x32_bf16(af[im], bfr[in], acc[im][in], 0, 0, 0);
        __syncthreads();
    }

    // epilogue: D = nA + nB - 2*dot -> exp -> predicate -> bucket sums
    float inv_scale = invscale_p[0];
    int ibase = i0 + wr * 64;
    int jbase = j0 + wc * 64;
    float nBv[4];
    int labBv[4], grpBv[4];
#pragma unroll
    for (int in = 0; in < 4; ++in) {
        int j = jbase + in * 16 + l15;
        nBv[in] = nB[j];
        labBv[in] = labels[j];
        grpBv[in] = groups[j];
    }
    float cs[4] = {0.0f, 0.0f, 0.0f, 0.0f};   // sym col sums (c > r)
#pragma unroll
    for (int im = 0; im < 4; ++im) {
#pragma unroll
        for (int j = 0; j < 4; ++j) {
            int row = ibase + im * 16 + l4 * 4 + j;
            float ni = nA[row];
            int li = labels[row];
            int gi = groups[row];
            float s0 = 0.0f, s1 = 0.0f;
#pragma unroll
            for (int in = 0; in < 4; ++in) {
                float d = ni + nBv[in] - 2.0f * acc[im][in][j];
                d = fmaxf(d, 1e-12f);
                float kv = __expf(-d * inv_scale);
                bool ok = (li == labBv[in]);
                if (mode == 1) ok = ok && (gi == grpBv[in]);
                if (mode == 2) {
                    s0 += (ok && grpBv[in] == 0) ? kv : 0.0f;
                    s1 += (ok && grpBv[in] == 1) ? kv : 0.0f;
                } else {
                    int c = jbase + in * 16 + l15;
                    s0     += (ok && c >= row) ? kv : 0.0f;
                    cs[in] += (ok && c >  row) ? kv : 0.0f;
                }
            }
#pragma unroll
            for (int o = 1; o < 16; o <<= 1) {
                s0 += __shfl_xor(s0, o);
                if (mode == 2) s1 += __shfl_xor(s1, o);
            }
            if (l15 == 0) {
                if (mode == 0)      atomicAdd(&lbkt[li], s0);
                else if (mode == 1) atomicAdd(&lbkt[2 * li + gi], s0);
                else {
                    atomicAdd(&lbkt[2 * li],     s0);
                    atomicAdd(&lbkt[2 * li + 1], s1);
                }
            }
        }
    }
    if (mode != 2) {
#pragma unroll
        for (int in = 0; in < 4; ++in) {
            cs[in] += __shfl_xor(cs[in], 16);
            cs[in] += __shfl_xor(cs[in], 32);
        }
        if (l4 == 0) {
#pragma unroll
            for (int in = 0; in < 4; ++in) {
                int bkt = (mode == 0) ? labBv[in] : (2 * labBv[in] + grpBv[in]);
                atomicAdd(&lbkt[bkt], cs[in]);
            }
        }
    }
    __syncthreads();
    int lim = (mode == 0) ? 10 : 20;
    if (tid < lim) {
        int off = (mode == 0) ? 0 : ((mode == 1) ? 10 : 30);
        atomicAdd(&gbkt[off + tid], lbkt[tid]);
    }
}

// ---------------------------------------------------------------------------
// Kernel 4: final combine. Counts labels/groups (register buckets,
// compile-time indices) + reads gbkt[50] -> scalar loss.
// ---------------------------------------------------------------------------
__global__ void k_out(const int* __restrict__ labels, const int* __restrict__ groups,
                      const float* __restrict__ gbkt, float* __restrict__ out) {
    __shared__ float red[30];
    int tid = threadIdx.x;
    float cT[NC] = {}, cS[NC * NG] = {};
    for (int i = tid; i < NN; i += 256) {
        int l = labels[i], g = groups[i];
#pragma unroll
        for (int c = 0; c < NC; ++c) {
            bool m = (l == c);
            cT[c]         += m ? 1.0f : 0.0f;
            cS[2 * c]     += (m && g == 0) ? 1.0f : 0.0f;
            cS[2 * c + 1] += (m && g == 1) ? 1.0f : 0.0f;
        }
    }
#pragma unroll
    for (int o = 32; o; o >>= 1) {
#pragma unroll
        for (int c = 0; c < NC; ++c) cT[c] += __shfl_xor(cT[c], o);
#pragma unroll
        for (int p = 0; p < NC * NG; ++p) cS[p] += __shfl_xor(cS[p], o);
    }
    if (tid < 30) red[tid] = 0.0f;
    __syncthreads();
    if ((tid & 63) == 0) {
#pragma unroll
        for (int c = 0; c < NC; ++c) atomicAdd(&red[c], cT[c]);
#pragma unroll
        for (int p = 0; p < NC * NG; ++p) atomicAdd(&red[10 + p], cS[p]);
    }
    __syncthreads();
    if (tid == 0) {
        float total = 0.0f;
        for (int c = 0; c < NC; ++c) {
            float ntc = red[c];
            float sn = fmaxf(ntc, 1.0f);
            float meanTT = gbkt[c] / (sn * sn);
            for (int g = 0; g < NG; ++g) {
                float nsg = red[10 + 2 * c + g];
                float ss = fmaxf(nsg, 1.0f);
                float meanSS = gbkt[10 + 2 * c + g] / (ss * ss);
                float meanTS = gbkt[30 + 2 * c + g] / (sn * ss);
                if (ntc > 0.0f && nsg > 0.0f)
                    total += meanTT + meanSS - 2.0f * meanTS;
            }
        }
        out[0] = 0.5f * total;
    }
}

// ---------------------------------------------------------------------------
// workspace layout:
// bytes [0, 4MB)      : teacher bf16 [4096][512]
// bytes [4MB, 8MB)    : student bf16 [4096][512]
// floats from 8MB (wsf):
//   +0      nt[4096]
//   +4096   ns[4096]
//   +8192   gbkt[64]       <- zero region start (68 floats: buckets+invscale+cnt)
//   +8256   invscale[1]
//   +8257   cnt (uint)     <- zero region end
//   +8260   psum[64*512]   (fully overwritten each call)
// ---------------------------------------------------------------------------
extern "C" void kernel_launch(void* const* d_in, const int* in_sizes, int n_in,
                              void* d_out, int out_size, void* d_ws, size_t ws_size,
                              hipStream_t stream) {
    const float* fs     = (const float*)d_in[0];
    const float* ft     = (const float*)d_in[1];
    const int*   groups = (const int*)d_in[2];
    const int*   labels = (const int*)d_in[3];

    __bf16* Abf = (__bf16*)d_ws;                       // teacher
    __bf16* Bbf = (__bf16*)d_ws + (size_t)NN * DD;     // student
    float* wsf  = (float*)((char*)d_ws + (size_t)2 * NN * DD * sizeof(__bf16));
    float* nt   = wsf;
    float* ns   = wsf + 4096;
    float* gbkt = wsf + 8192;
    float* invs = wsf + 8256;
    unsigned int* cnt = (unsigned int*)(wsf + 8257);
    float* psum = wsf + 8260;

    k_prep<<<2048, 256, 0, stream>>>(ft, fs, Abf, Bbf, nt, ns, gbkt);
    k_colsums_scale<<<64, 256, 0, stream>>>(ft, fs, psum, nt, ns, invs, cnt);
    k_gram_all<<<NTILES, 256, 0, stream>>>(Abf, Bbf, nt, ns, labels, groups,
                                           invs, gbkt);
    k_out<<<1, 256, 0, stream>>>(labels, groups, gbkt, (float*)d_out);
}

// Round 15
// 146.933 us; speedup vs baseline: 1.5908x; 1.0308x over previous
//
#include <hip/hip_runtime.h>
#include <math.h>

#define NN 4096
#define DD 512
#define NC 10
#define NG 2

#define BM 128
#define BN 128
#define BK 32
#define NT (DD / BK)     // 16 K-steps
#define NTILES 2080      // 528 TT + 528 SS + 1024 TS (= 8 * 260)

typedef __bf16 bf16x8 __attribute__((ext_vector_type(8)));
typedef __bf16 bf16x4 __attribute__((ext_vector_type(4)));
typedef float f32x4 __attribute__((ext_vector_type(4)));

__device__ __forceinline__ void load_lds16(const __bf16* g, __bf16* l) {
    __builtin_amdgcn_global_load_lds((const __attribute__((address_space(1))) void*)g,
                                     (__attribute__((address_space(3))) void*)l, 16, 0, 0);
}

__device__ __forceinline__ float agent_ld(const float* p) {
    return __hip_atomic_load(p, __ATOMIC_RELAXED, __HIP_MEMORY_SCOPE_AGENT);
}

// ---------------------------------------------------------------------------
// Kernel 1: fused fp32->bf16 convert + per-row squared norms (fp32 exact).
// ILP: each wave handles teacher row r AND student row r -> 4 float4 loads
// in flight (was 2). 1024 blocks x 4 waves. Block 0 zeroes bucket region.
// ---------------------------------------------------------------------------
__global__ void k_prep(const float* __restrict__ ft, const float* __restrict__ fs,
                       __bf16* __restrict__ at, __bf16* __restrict__ as_,
                       float* __restrict__ nt, float* __restrict__ ns,
                       float* __restrict__ zero_base) {
    if (blockIdx.x == 0 && threadIdx.x < 68) zero_base[threadIdx.x] = 0.0f;
    int wid  = threadIdx.x >> 6;
    int lane = threadIdx.x & 63;
    int r = blockIdx.x * 4 + wid;             // 0..4095
    const float4* pt = (const float4*)(ft + (size_t)r * DD);
    const float4* ps = (const float4*)(fs + (size_t)r * DD);
    float st = 0.0f, ss = 0.0f;
#pragma unroll
    for (int c = 0; c < 2; ++c) {
        float4 vt = pt[lane + 64 * c];
        float4 vs = ps[lane + 64 * c];
        st += vt.x * vt.x + vt.y * vt.y + vt.z * vt.z + vt.w * vt.w;
        ss += vs.x * vs.x + vs.y * vs.y + vs.z * vs.z + vs.w * vs.w;
        bf16x4 bt, bs;
        bt[0] = (__bf16)vt.x; bt[1] = (__bf16)vt.y; bt[2] = (__bf16)vt.z; bt[3] = (__bf16)vt.w;
        bs[0] = (__bf16)vs.x; bs[1] = (__bf16)vs.y; bs[2] = (__bf16)vs.z; bs[3] = (__bf16)vs.w;
        *(bf16x4*)(at  + (size_t)r * DD + (lane + 64 * c) * 4) = bt;
        *(bf16x4*)(as_ + (size_t)r * DD + (lane + 64 * c) * 4) = bs;
    }
#pragma unroll
    for (int o = 32; o; o >>= 1) { st += __shfl_xor(st, o); ss += __shfl_xor(ss, o); }
    if (lane == 0) { nt[r] = st; ns[r] = ss; }
}

// ---------------------------------------------------------------------------
// Kernel 2: column partial sums from the BF16 copies (8 MB, cache-hot; sigma
// shift from bf16 rounding ~3e-5 relative) + last-finisher computes sigma
// (closed form) -> invscale. 64 blocks; fence protocol cheap here.
// ---------------------------------------------------------------------------
__global__ void k_colsums_scale(const __bf16* __restrict__ at, const __bf16* __restrict__ as_,
                                float* __restrict__ psum,
                                const float* __restrict__ nt, const float* __restrict__ ns,
                                float* __restrict__ invscale, unsigned int* __restrict__ cnt) {
    int b = blockIdx.x;                     // 0..63
    const __bf16* src = (b < 32) ? at : as_;
    int r0 = (b & 31) * 128;
    int c0 = threadIdx.x, c1 = threadIdx.x + 256;
    float a0 = 0.0f, a1 = 0.0f;
    for (int r = r0; r < r0 + 128; ++r) {
        a0 += (float)src[(size_t)r * DD + c0];
        a1 += (float)src[(size_t)r * DD + c1];
    }
    psum[(size_t)b * 512 + c0] = a0;
    psum[(size_t)b * 512 + c1] = a1;

    __shared__ int amLast;
    __threadfence();
    __syncthreads();
    if (threadIdx.x == 0) amLast = (atomicAdd(cnt, 1u) == 63u) ? 1 : 0;
    __syncthreads();
    if (!amLast) return;
    __threadfence();

    __shared__ float red[8];
    int tid = threadIdx.x;
    float s = 0.0f;
    for (int i = tid; i < NN; i += 256) s += nt[i] + ns[i];
    float d = 0.0f;
    for (int col = tid; col < DD; col += 256) {
        float st = 0.0f, su = 0.0f;
#pragma unroll
        for (int p = 0; p < 32; ++p) {
            st += agent_ld(&psum[(size_t)p * 512 + col]);
            su += agent_ld(&psum[(size_t)(p + 32) * 512 + col]);
        }
        d += st * su;
    }
#pragma unroll
    for (int o = 32; o; o >>= 1) { s += __shfl_xor(s, o); d += __shfl_xor(d, o); }
    int wid = tid >> 6, lane = tid & 63;
    if (lane == 0) { red[wid] = s; red[wid + 4] = d; }
    __syncthreads();
    if (tid == 0) {
        float S  = red[0] + red[1] + red[2] + red[3];
        float Dt = red[4] + red[5] + red[6] + red[7];
        float sigma = S / (float)NN - 2.0f * Dt / ((float)NN * (float)NN);
        invscale[0] = 1.0f / (2.0f * sigma);
    }
}

// ---------------------------------------------------------------------------
// Kernel 3: all three Grams. r14's shape/epilogue + r5's proven 3-buffer
// depth-2 counted-vmcnt pipeline (single-variable swap):
//   prologue: STAGE(0,t0); STAGE(1,t1); vmcnt(4); barrier
//   step t: ds_read buf[t%3]; STAGE(buf[(t+2)%3], t+2); MFMA;
//           vmcnt(4|0); barrier   <- t+2's 4 loads stay in flight
// 128x128, 4 waves (2x2), wave tile 64x64, BK=32, 48 KB LDS (3 blocks/CU),
// conflict-free [kq][row][8], swz=(bid&7)*260+bid>>3.
// Epilogue: LDS bucket reduce -> <=20 global atomics into gbkt[50].
// ---------------------------------------------------------------------------
__global__ __launch_bounds__(256, 3) void k_gram_all(
    const __bf16* __restrict__ T, const __bf16* __restrict__ S,
    const float* __restrict__ nt, const float* __restrict__ ns,
    const int* __restrict__ labels, const int* __restrict__ groups,
    const float* __restrict__ invscale_p, float* __restrict__ gbkt) {

    __shared__ __bf16 As[3][4 * 128 * 8];   // 8 KB per buffer
    __shared__ __bf16 Bs[3][4 * 128 * 8];   // 8 KB per buffer
    __shared__ float lbkt[20];

    int swz = ((int)blockIdx.x & 7) * 260 + ((int)blockIdx.x >> 3);
    int mode, bi, bj;
    if (swz < 1056) {
        mode = (swz < 528) ? 0 : 1;
        int k = (swz < 528) ? swz : swz - 528;
        int t = 0;
        while (k >= 32 - t) { k -= 32 - t; ++t; }   // uniform, <=32 iters
        bi = t; bj = t + k;
    } else {
        mode = 2;
        int k = swz - 1056;
        bi = k >> 5; bj = k & 31;
    }

    const __bf16* A = (mode == 1) ? S : T;
    const __bf16* B = (mode == 0) ? T : S;
    const float* nA = (mode == 1) ? ns : nt;
    const float* nB = (mode == 0) ? nt : ns;

    int tid = threadIdx.x;
    if (tid < 20) lbkt[tid] = 0.0f;          // covered by prologue barrier
    int i0 = bi * BM;
    int j0 = bj * BN;

    int lane = tid & 63, wid = tid >> 6;
    int wr = wid >> 1, wc = wid & 1;          // 2 x 2 wave grid
    int l15 = lane & 15, l4 = lane >> 4;

    int ra = tid & 127;
    int qa = tid >> 7;                        // 0..1
    const __bf16* gA = A + (size_t)(i0 + ra) * DD + qa * 8;   // +16 = chunk qa+2
    const __bf16* gB = B + (size_t)(j0 + ra) * DD + qa * 8;

    f32x4 acc[4][4] = {};

#define STAGE(bb, tt)                                                          \
    do {                                                                       \
        int _k0 = (tt) * BK;                                                   \
        load_lds16(gA + _k0,      &As[(bb)][(size_t)tid * 8]);                 \
        load_lds16(gA + _k0 + 16, &As[(bb)][(size_t)(tid + 256) * 8]);         \
        load_lds16(gB + _k0,      &Bs[(bb)][(size_t)tid * 8]);                 \
        load_lds16(gB + _k0 + 16, &Bs[(bb)][(size_t)(tid + 256) * 8]);         \
    } while (0)

    // prologue: stage tiles 0,1 -> bufs 0,1; wait tile0 (tile1 stays in flight)
    STAGE(0, 0);
    STAGE(1, 1);
    asm volatile("s_waitcnt vmcnt(4)" ::: "memory");
    __builtin_amdgcn_s_barrier();
    __builtin_amdgcn_sched_barrier(0);

#pragma unroll
    for (int t = 0; t < NT; ++t) {
        int b = t % 3;
        bf16x8 af[4], bfr[4];
#pragma unroll
        for (int im = 0; im < 4; ++im)
            af[im] = *(const bf16x8*)&As[b][((size_t)l4 * 128 + wr * 64 + im * 16 + l15) * 8];
#pragma unroll
        for (int in = 0; in < 4; ++in)
            bfr[in] = *(const bf16x8*)&Bs[b][((size_t)l4 * 128 + wc * 64 + in * 16 + l15) * 8];
        if (t + 2 < NT) STAGE((t + 2) % 3, t + 2);
#pragma unroll
        for (int im = 0; im < 4; ++im)
#pragma unroll
            for (int in = 0; in < 4; ++in)
                acc[im][in] = __builtin_amdgcn_mfma_f32_16x16x32_bf16(af[im], bfr[in], acc[im][in], 0, 0, 0);
        if (t + 1 < NT) {
            if (t + 2 < NT) asm volatile("s_waitcnt vmcnt(4)" ::: "memory");
            else            asm volatile("s_waitcnt vmcnt(0)" ::: "memory");
            __builtin_amdgcn_s_barrier();
            __builtin_amdgcn_sched_barrier(0);
        }
    }
#undef STAGE

    // epilogue: D = nA + nB - 2*dot -> exp -> predicate -> bucket sums
    float inv_scale = invscale_p[0];
    int ibase = i0 + wr * 64;
    int jbase = j0 + wc * 64;
    float nBv[4];
    int labBv[4], grpBv[4];
#pragma unroll
    for (int in = 0; in < 4; ++in) {
        int j = jbase + in * 16 + l15;
        nBv[in] = nB[j];
        labBv[in] = labels[j];
        grpBv[in] = groups[j];
    }
    float cs[4] = {0.0f, 0.0f, 0.0f, 0.0f};   // sym col sums (c > r)
#pragma unroll
    for (int im = 0; im < 4; ++im) {
#pragma unroll
        for (int j = 0; j < 4; ++j) {
            int row = ibase + im * 16 + l4 * 4 + j;
            float ni = nA[row];
            int li = labels[row];
            int gi = groups[row];
            float s0 = 0.0f, s1 = 0.0f;
#pragma unroll
            for (int in = 0; in < 4; ++in) {
                float d = ni + nBv[in] - 2.0f * acc[im][in][j];
                d = fmaxf(d, 1e-12f);
                float kv = __expf(-d * inv_scale);
                bool ok = (li == labBv[in]);
                if (mode == 1) ok = ok && (gi == grpBv[in]);
                if (mode == 2) {
                    s0 += (ok && grpBv[in] == 0) ? kv : 0.0f;
                    s1 += (ok && grpBv[in] == 1) ? kv : 0.0f;
                } else {
                    int c = jbase + in * 16 + l15;
                    s0     += (ok && c >= row) ? kv : 0.0f;
                    cs[in] += (ok && c >  row) ? kv : 0.0f;
                }
            }
#pragma unroll
            for (int o = 1; o < 16; o <<= 1) {
                s0 += __shfl_xor(s0, o);
                if (mode == 2) s1 += __shfl_xor(s1, o);
            }
            if (l15 == 0) {
                if (mode == 0)      atomicAdd(&lbkt[li], s0);
                else if (mode == 1) atomicAdd(&lbkt[2 * li + gi], s0);
                else {
                    atomicAdd(&lbkt[2 * li],     s0);
                    atomicAdd(&lbkt[2 * li + 1], s1);
                }
            }
        }
    }
    if (mode != 2) {
#pragma unroll
        for (int in = 0; in < 4; ++in) {
            cs[in] += __shfl_xor(cs[in], 16);
            cs[in] += __shfl_xor(cs[in], 32);
        }
        if (l4 == 0) {
#pragma unroll
            for (int in = 0; in < 4; ++in) {
                int bkt = (mode == 0) ? labBv[in] : (2 * labBv[in] + grpBv[in]);
                atomicAdd(&lbkt[bkt], cs[in]);
            }
        }
    }
    __syncthreads();
    int lim = (mode == 0) ? 10 : 20;
    if (tid < lim) {
        int off = (mode == 0) ? 0 : ((mode == 1) ? 10 : 30);
        atomicAdd(&gbkt[off + tid], lbkt[tid]);
    }
}

// ---------------------------------------------------------------------------
// Kernel 4: final combine. Counts labels/groups (register buckets,
// compile-time indices) + reads gbkt[50] -> scalar loss. (unchanged)
// ---------------------------------------------------------------------------
__global__ void k_out(const int* __restrict__ labels, const int* __restrict__ groups,
                      const float* __restrict__ gbkt, float* __restrict__ out) {
    __shared__ float red[30];
    int tid = threadIdx.x;
    float cT[NC] = {}, cS[NC * NG] = {};
    for (int i = tid; i < NN; i += 256) {
        int l = labels[i], g = groups[i];
#pragma unroll
        for (int c = 0; c < NC; ++c) {
            bool m = (l == c);
            cT[c]         += m ? 1.0f : 0.0f;
            cS[2 * c]     += (m && g == 0) ? 1.0f : 0.0f;
            cS[2 * c + 1] += (m && g == 1) ? 1.0f : 0.0f;
        }
    }
#pragma unroll
    for (int o = 32; o; o >>= 1) {
#pragma unroll
        for (int c = 0; c < NC; ++c) cT[c] += __shfl_xor(cT[c], o);
#pragma unroll
        for (int p = 0; p < NC * NG; ++p) cS[p] += __shfl_xor(cS[p], o);
    }
    if (tid < 30) red[tid] = 0.0f;
    __syncthreads();
    if ((tid & 63) == 0) {
#pragma unroll
        for (int c = 0; c < NC; ++c) atomicAdd(&red[c], cT[c]);
#pragma unroll
        for (int p = 0; p < NC * NG; ++p) atomicAdd(&red[10 + p], cS[p]);
    }
    __syncthreads();
    if (tid == 0) {
        float total = 0.0f;
        for (int c = 0; c < NC; ++c) {
            float ntc = red[c];
            float sn = fmaxf(ntc, 1.0f);
            float meanTT = gbkt[c] / (sn * sn);
            for (int g = 0; g < NG; ++g) {
                float nsg = red[10 + 2 * c + g];
                float ss = fmaxf(nsg, 1.0f);
                float meanSS = gbkt[10 + 2 * c + g] / (ss * ss);
                float meanTS = gbkt[30 + 2 * c + g] / (sn * ss);
                if (ntc > 0.0f && nsg > 0.0f)
                    total += meanTT + meanSS - 2.0f * meanTS;
            }
        }
        out[0] = 0.5f * total;
    }
}

// ---------------------------------------------------------------------------
// workspace layout:
// bytes [0, 4MB)      : teacher bf16 [4096][512]
// bytes [4MB, 8MB)    : student bf16 [4096][512]
// floats from 8MB (wsf):
//   +0      nt[4096]
//   +4096   ns[4096]
//   +8192   gbkt[64]       <- zero region start (68 floats: buckets+invscale+cnt)
//   +8256   invscale[1]
//   +8257   cnt (uint)     <- zero region end
//   +8260   psum[64*512]   (fully overwritten each call)
// ---------------------------------------------------------------------------
extern "C" void kernel_launch(void* const* d_in, const int* in_sizes, int n_in,
                              void* d_out, int out_size, void* d_ws, size_t ws_size,
                              hipStream_t stream) {
    const float* fs     = (const float*)d_in[0];
    const float* ft     = (const float*)d_in[1];
    const int*   groups = (const int*)d_in[2];
    const int*   labels = (const int*)d_in[3];

    __bf16* Abf = (__bf16*)d_ws;                       // teacher
    __bf16* Bbf = (__bf16*)d_ws + (size_t)NN * DD;     // student
    float* wsf  = (float*)((char*)d_ws + (size_t)2 * NN * DD * sizeof(__bf16));
    float* nt   = wsf;
    float* ns   = wsf + 4096;
    float* gbkt = wsf + 8192;
    float* invs = wsf + 8256;
    unsigned int* cnt = (unsigned int*)(wsf + 8257);
    float* psum = wsf + 8260;

    k_prep<<<1024, 256, 0, stream>>>(ft, fs, Abf, Bbf, nt, ns, gbkt);
    k_colsums_scale<<<64, 256, 0, stream>>>(Abf, Bbf, psum, nt, ns, invs, cnt);
    k_gram_all<<<NTILES, 256, 0, stream>>>(Abf, Bbf, nt, ns, labels, groups,
                                           invs, gbkt);
    k_out<<<1, 256, 0, stream>>>(labels, groups, gbkt, (float*)d_out);
}

// Round 16
// 142.352 us; speedup vs baseline: 1.6420x; 1.0322x over previous
//
#include <hip/hip_runtime.h>
#include <math.h>

#define NN 4096
#define DD 512
#define NC 10
#define NG 2

#define BM 128
#define BN 128
#define BK 32
#define NT (DD / BK)     // 16 K-steps
#define NTILES 2080      // 528 TT + 528 SS + 1024 TS (= 8 * 260)

typedef __bf16 bf16x8 __attribute__((ext_vector_type(8)));
typedef __bf16 bf16x4 __attribute__((ext_vector_type(4)));
typedef float f32x4 __attribute__((ext_vector_type(4)));

__device__ __forceinline__ void load_lds16(const __bf16* g, __bf16* l) {
    __builtin_amdgcn_global_load_lds((const __attribute__((address_space(1))) void*)g,
                                     (__attribute__((address_space(3))) void*)l, 16, 0, 0);
}

__device__ __forceinline__ float agent_ld(const float* p) {
    return __hip_atomic_load(p, __ATOMIC_RELAXED, __HIP_MEMORY_SCOPE_AGENT);
}

// ---------------------------------------------------------------------------
// Kernel 1 (fused): fp32->bf16 convert + per-row squared norms (all 1024
// blocks) + column sums / sum-of-squares partials (blocks 0..63; coalesced
// thread-per-column fp32 reads) + last-heavy-block computes invscale.
// Counter is pre-zeroed by a hipMemsetAsync node. Block 0 zeroes gbkt.
// ---------------------------------------------------------------------------
__global__ void k_prep(const float* __restrict__ ft, const float* __restrict__ fs,
                       __bf16* __restrict__ at, __bf16* __restrict__ as_,
                       float* __restrict__ nt, float* __restrict__ ns,
                       float* __restrict__ psum, float* __restrict__ ssq,
                       float* __restrict__ gbkt, float* __restrict__ invscale,
                       unsigned int* __restrict__ cnt) {
    int tid = threadIdx.x;
    if (blockIdx.x == 0 && tid < 64) gbkt[tid] = 0.0f;

    // ---- light work: norms + convert for teacher & student row r ----
    int wid  = tid >> 6;
    int lane = tid & 63;
    int r = blockIdx.x * 4 + wid;             // 0..4095
    const float4* pt = (const float4*)(ft + (size_t)r * DD);
    const float4* ps = (const float4*)(fs + (size_t)r * DD);
    float st = 0.0f, ss = 0.0f;
#pragma unroll
    for (int c = 0; c < 2; ++c) {
        float4 vt = pt[lane + 64 * c];
        float4 vs = ps[lane + 64 * c];
        st += vt.x * vt.x + vt.y * vt.y + vt.z * vt.z + vt.w * vt.w;
        ss += vs.x * vs.x + vs.y * vs.y + vs.z * vs.z + vs.w * vs.w;
        bf16x4 bt, bs;
        bt[0] = (__bf16)vt.x; bt[1] = (__bf16)vt.y; bt[2] = (__bf16)vt.z; bt[3] = (__bf16)vt.w;
        bs[0] = (__bf16)vs.x; bs[1] = (__bf16)vs.y; bs[2] = (__bf16)vs.z; bs[3] = (__bf16)vs.w;
        *(bf16x4*)(at  + (size_t)r * DD + (lane + 64 * c) * 4) = bt;
        *(bf16x4*)(as_ + (size_t)r * DD + (lane + 64 * c) * 4) = bs;
    }
#pragma unroll
    for (int o = 32; o; o >>= 1) { st += __shfl_xor(st, o); ss += __shfl_xor(ss, o); }
    if (lane == 0) { nt[r] = st; ns[r] = ss; }

    // ---- heavy work: blocks 0..63 compute column sums + sumsq partials ----
    if (blockIdx.x >= 64) return;
    int b = blockIdx.x;
    const float* src = (b < 32) ? ft : fs;
    int r0 = (b & 31) * 128;
    int c0 = tid, c1 = tid + 256;
    float a0 = 0.0f, a1 = 0.0f, sq = 0.0f;
    for (int rr = r0; rr < r0 + 128; ++rr) {
        float v0 = src[(size_t)rr * DD + c0];
        float v1 = src[(size_t)rr * DD + c1];
        a0 += v0; a1 += v1;
        sq += v0 * v0 + v1 * v1;
    }
    psum[(size_t)b * 512 + c0] = a0;
    psum[(size_t)b * 512 + c1] = a1;
#pragma unroll
    for (int o = 32; o; o >>= 1) sq += __shfl_xor(sq, o);
    __shared__ float redsq[4];
    if (lane == 0) redsq[wid] = sq;
    __syncthreads();
    if (tid == 0) ssq[b] = redsq[0] + redsq[1] + redsq[2] + redsq[3];

    // ---- last-heavy-block: sigma (closed form) -> invscale ----
    __shared__ int amLast;
    __threadfence();
    __syncthreads();
    if (tid == 0) amLast = (atomicAdd(cnt, 1u) == 63u) ? 1 : 0;
    __syncthreads();
    if (!amLast) return;
    __threadfence();

    __shared__ float red[8];
    float s = (tid < 64) ? agent_ld(&ssq[tid]) : 0.0f;   // Σ|t|^2 + Σ|s|^2
    float d = 0.0f;
    for (int col = tid; col < DD; col += 256) {
        float su = 0.0f, sv = 0.0f;
#pragma unroll
        for (int p = 0; p < 32; ++p) {
            su += agent_ld(&psum[(size_t)p * 512 + col]);
            sv += agent_ld(&psum[(size_t)(p + 32) * 512 + col]);
        }
        d += su * sv;
    }
#pragma unroll
    for (int o = 32; o; o >>= 1) { s += __shfl_xor(s, o); d += __shfl_xor(d, o); }
    if (lane == 0) { red[wid] = s; red[wid + 4] = d; }
    __syncthreads();
    if (tid == 0) {
        float S  = red[0] + red[1] + red[2] + red[3];
        float Dt = red[4] + red[5] + red[6] + red[7];
        float sigma = S / (float)NN - 2.0f * Dt / ((float)NN * (float)NN);
        invscale[0] = 1.0f / (2.0f * sigma);
    }
}

// ---------------------------------------------------------------------------
// Kernel 2: all three Grams. BYTE-IDENTICAL to round 15 (best measured):
// 128x128, 4 waves (2x2), wave tile 64x64, BK=32, 3-buffer depth-2
// counted-vmcnt pipeline (steady vmcnt(4)), conflict-free [kq][row][8] LDS,
// swz=(bid&7)*260+bid>>3; LDS bucket epilogue -> <=20 atomics into gbkt[50].
// ---------------------------------------------------------------------------
__global__ __launch_bounds__(256, 3) void k_gram_all(
    const __bf16* __restrict__ T, const __bf16* __restrict__ S,
    const float* __restrict__ nt, const float* __restrict__ ns,
    const int* __restrict__ labels, const int* __restrict__ groups,
    const float* __restrict__ invscale_p, float* __restrict__ gbkt) {

    __shared__ __bf16 As[3][4 * 128 * 8];   // 8 KB per buffer
    __shared__ __bf16 Bs[3][4 * 128 * 8];   // 8 KB per buffer
    __shared__ float lbkt[20];

    int swz = ((int)blockIdx.x & 7) * 260 + ((int)blockIdx.x >> 3);
    int mode, bi, bj;
    if (swz < 1056) {
        mode = (swz < 528) ? 0 : 1;
        int k = (swz < 528) ? swz : swz - 528;
        int t = 0;
        while (k >= 32 - t) { k -= 32 - t; ++t; }   // uniform, <=32 iters
        bi = t; bj = t + k;
    } else {
        mode = 2;
        int k = swz - 1056;
        bi = k >> 5; bj = k & 31;
    }

    const __bf16* A = (mode == 1) ? S : T;
    const __bf16* B = (mode == 0) ? T : S;
    const float* nA = (mode == 1) ? ns : nt;
    const float* nB = (mode == 0) ? nt : ns;

    int tid = threadIdx.x;
    if (tid < 20) lbkt[tid] = 0.0f;          // covered by prologue barrier
    int i0 = bi * BM;
    int j0 = bj * BN;

    int lane = tid & 63, wid = tid >> 6;
    int wr = wid >> 1, wc = wid & 1;          // 2 x 2 wave grid
    int l15 = lane & 15, l4 = lane >> 4;

    int ra = tid & 127;
    int qa = tid >> 7;                        // 0..1
    const __bf16* gA = A + (size_t)(i0 + ra) * DD + qa * 8;   // +16 = chunk qa+2
    const __bf16* gB = B + (size_t)(j0 + ra) * DD + qa * 8;

    f32x4 acc[4][4] = {};

#define STAGE(bb, tt)                                                          \
    do {                                                                       \
        int _k0 = (tt) * BK;                                                   \
        load_lds16(gA + _k0,      &As[(bb)][(size_t)tid * 8]);                 \
        load_lds16(gA + _k0 + 16, &As[(bb)][(size_t)(tid + 256) * 8]);         \
        load_lds16(gB + _k0,      &Bs[(bb)][(size_t)tid * 8]);                 \
        load_lds16(gB + _k0 + 16, &Bs[(bb)][(size_t)(tid + 256) * 8]);         \
    } while (0)

    STAGE(0, 0);
    STAGE(1, 1);
    asm volatile("s_waitcnt vmcnt(4)" ::: "memory");
    __builtin_amdgcn_s_barrier();
    __builtin_amdgcn_sched_barrier(0);

#pragma unroll
    for (int t = 0; t < NT; ++t) {
        int b = t % 3;
        bf16x8 af[4], bfr[4];
#pragma unroll
        for (int im = 0; im < 4; ++im)
            af[im] = *(const bf16x8*)&As[b][((size_t)l4 * 128 + wr * 64 + im * 16 + l15) * 8];
#pragma unroll
        for (int in = 0; in < 4; ++in)
            bfr[in] = *(const bf16x8*)&Bs[b][((size_t)l4 * 128 + wc * 64 + in * 16 + l15) * 8];
        if (t + 2 < NT) STAGE((t + 2) % 3, t + 2);
#pragma unroll
        for (int im = 0; im < 4; ++im)
#pragma unroll
            for (int in = 0; in < 4; ++in)
                acc[im][in] = __builtin_amdgcn_mfma_f32_16x16x32_bf16(af[im], bfr[in], acc[im][in], 0, 0, 0);
        if (t + 1 < NT) {
            if (t + 2 < NT) asm volatile("s_waitcnt vmcnt(4)" ::: "memory");
            else            asm volatile("s_waitcnt vmcnt(0)" ::: "memory");
            __builtin_amdgcn_s_barrier();
            __builtin_amdgcn_sched_barrier(0);
        }
    }
#undef STAGE

    // epilogue: D = nA + nB - 2*dot -> exp -> predicate -> bucket sums
    float inv_scale = invscale_p[0];
    int ibase = i0 + wr * 64;
    int jbase = j0 + wc * 64;
    float nBv[4];
    int labBv[4], grpBv[4];
#pragma unroll
    for (int in = 0; in < 4; ++in) {
        int j = jbase + in * 16 + l15;
        nBv[in] = nB[j];
        labBv[in] = labels[j];
        grpBv[in] = groups[j];
    }
    float cs[4] = {0.0f, 0.0f, 0.0f, 0.0f};   // sym col sums (c > r)
#pragma unroll
    for (int im = 0; im < 4; ++im) {
#pragma unroll
        for (int j = 0; j < 4; ++j) {
            int row = ibase + im * 16 + l4 * 4 + j;
            float ni = nA[row];
            int li = labels[row];
            int gi = groups[row];
            float s0 = 0.0f, s1 = 0.0f;
#pragma unroll
            for (int in = 0; in < 4; ++in) {
                float d = ni + nBv[in] - 2.0f * acc[im][in][j];
                d = fmaxf(d, 1e-12f);
                float kv = __expf(-d * inv_scale);
                bool ok = (li == labBv[in]);
                if (mode == 1) ok = ok && (gi == grpBv[in]);
                if (mode == 2) {
                    s0 += (ok && grpBv[in] == 0) ? kv : 0.0f;
                    s1 += (ok && grpBv[in] == 1) ? kv : 0.0f;
                } else {
                    int c = jbase + in * 16 + l15;
                    s0     += (ok && c >= row) ? kv : 0.0f;
                    cs[in] += (ok && c >  row) ? kv : 0.0f;
                }
            }
#pragma unroll
            for (int o = 1; o < 16; o <<= 1) {
                s0 += __shfl_xor(s0, o);
                if (mode == 2) s1 += __shfl_xor(s1, o);
            }
            if (l15 == 0) {
                if (mode == 0)      atomicAdd(&lbkt[li], s0);
                else if (mode == 1) atomicAdd(&lbkt[2 * li + gi], s0);
                else {
                    atomicAdd(&lbkt[2 * li],     s0);
                    atomicAdd(&lbkt[2 * li + 1], s1);
                }
            }
        }
    }
    if (mode != 2) {
#pragma unroll
        for (int in = 0; in < 4; ++in) {
            cs[in] += __shfl_xor(cs[in], 16);
            cs[in] += __shfl_xor(cs[in], 32);
        }
        if (l4 == 0) {
#pragma unroll
            for (int in = 0; in < 4; ++in) {
                int bkt = (mode == 0) ? labBv[in] : (2 * labBv[in] + grpBv[in]);
                atomicAdd(&lbkt[bkt], cs[in]);
            }
        }
    }
    __syncthreads();
    int lim = (mode == 0) ? 10 : 20;
    if (tid < lim) {
        int off = (mode == 0) ? 0 : ((mode == 1) ? 10 : 30);
        atomicAdd(&gbkt[off + tid], lbkt[tid]);
    }
}

// ---------------------------------------------------------------------------
// Kernel 3: final combine. (unchanged from round 15)
// ---------------------------------------------------------------------------
__global__ void k_out(const int* __restrict__ labels, const int* __restrict__ groups,
                      const float* __restrict__ gbkt, float* __restrict__ out) {
    __shared__ float red[30];
    int tid = threadIdx.x;
    float cT[NC] = {}, cS[NC * NG] = {};
    for (int i = tid; i < NN; i += 256) {
        int l = labels[i], g = groups[i];
#pragma unroll
        for (int c = 0; c < NC; ++c) {
            bool m = (l == c);
            cT[c]         += m ? 1.0f : 0.0f;
            cS[2 * c]     += (m && g == 0) ? 1.0f : 0.0f;
            cS[2 * c + 1] += (m && g == 1) ? 1.0f : 0.0f;
        }
    }
#pragma unroll
    for (int o = 32; o; o >>= 1) {
#pragma unroll
        for (int c = 0; c < NC; ++c) cT[c] += __shfl_xor(cT[c], o);
#pragma unroll
        for (int p = 0; p < NC * NG; ++p) cS[p] += __shfl_xor(cS[p], o);
    }
    if (tid < 30) red[tid] = 0.0f;
    __syncthreads();
    if ((tid & 63) == 0) {
#pragma unroll
        for (int c = 0; c < NC; ++c) atomicAdd(&red[c], cT[c]);
#pragma unroll
        for (int p = 0; p < NC * NG; ++p) atomicAdd(&red[10 + p], cS[p]);
    }
    __syncthreads();
    if (tid == 0) {
        float total = 0.0f;
        for (int c = 0; c < NC; ++c) {
            float ntc = red[c];
            float sn = fmaxf(ntc, 1.0f);
            float meanTT = gbkt[c] / (sn * sn);
            for (int g = 0; g < NG; ++g) {
                float nsg = red[10 + 2 * c + g];
                float ss = fmaxf(nsg, 1.0f);
                float meanSS = gbkt[10 + 2 * c + g] / (ss * ss);
                float meanTS = gbkt[30 + 2 * c + g] / (sn * ss);
                if (ntc > 0.0f && nsg > 0.0f)
                    total += meanTT + meanSS - 2.0f * meanTS;
            }
        }
        out[0] = 0.5f * total;
    }
}

// ---------------------------------------------------------------------------
// workspace layout:
// bytes [0, 4MB)      : teacher bf16 [4096][512]
// bytes [4MB, 8MB)    : student bf16 [4096][512]
// floats from 8MB (wsf):
//   +0      nt[4096]
//   +4096   ns[4096]
//   +8192   gbkt[64]       (zeroed by prep block 0)
//   +8256   invscale[1]    (written by last heavy prep block)
//   +8257   cnt (uint)     (zeroed by hipMemsetAsync)
//   +8260   ssq[64]
//   +8324   psum[64*512]   (fully overwritten each call)
// ---------------------------------------------------------------------------
extern "C" void kernel_launch(void* const* d_in, const int* in_sizes, int n_in,
                              void* d_out, int out_size, void* d_ws, size_t ws_size,
                              hipStream_t stream) {
    const float* fs     = (const float*)d_in[0];
    const float* ft     = (const float*)d_in[1];
    const int*   groups = (const int*)d_in[2];
    const int*   labels = (const int*)d_in[3];

    __bf16* Abf = (__bf16*)d_ws;                       // teacher
    __bf16* Bbf = (__bf16*)d_ws + (size_t)NN * DD;     // student
    float* wsf  = (float*)((char*)d_ws + (size_t)2 * NN * DD * sizeof(__bf16));
    float* nt   = wsf;
    float* ns   = wsf + 4096;
    float* gbkt = wsf + 8192;
    float* invs = wsf + 8256;
    unsigned int* cnt = (unsigned int*)(wsf + 8257);
    float* ssq  = wsf + 8260;
    float* psum = wsf + 8324;

    hipMemsetAsync(cnt, 0, sizeof(unsigned int), stream);
    k_prep<<<1024, 256, 0, stream>>>(ft, fs, Abf, Bbf, nt, ns, psum, ssq,
                                     gbkt, invs, cnt);
    k_gram_all<<<NTILES, 256, 0, stream>>>(Abf, Bbf, nt, ns, labels, groups,
                                           invs, gbkt);
    k_out<<<1, 256, 0, stream>>>(labels, groups, gbkt, (float*)d_out);
}